// Round 1
// baseline (156.902 us; speedup 1.0000x reference)
//
#include <hip/hip_runtime.h>

// DispCorrLayer: out[b,d,h,w] = (1/C) * sum_c in1[b,c,h,w] * in2[b,c,h,w-(D-d)]
// (zero when w + d < D). B=4 C=32 H=256 W=512 D=128, fp32.

#define BB 4
#define CC 32
#define HH 256
#define WW 512
#define DD 128

#define WCHUNK 128           // w positions per block
#define TILE2  256           // in2 halo tile width = WCHUNK + 128
#define WT 4                 // w per thread
#define DT 16                // d per thread
#define NTHREADS 256

__global__ __launch_bounds__(NTHREADS)
void disp_corr_kernel(const float* __restrict__ in1,
                      const float* __restrict__ in2,
                      float* __restrict__ out) {
    __shared__ float s1[CC][WCHUNK];   // 16 KB
    __shared__ float s2[CC][TILE2];    // 32 KB

    const int tid = threadIdx.x;
    const int blk = blockIdx.x;              // 0..4095
    const int wc  = blk & 3;                 // w chunk index
    const int h   = (blk >> 2) & (HH - 1);
    const int b   = blk >> 10;
    const int wbase = wc * WCHUNK;

    // ---- stage in1 chunk: CC*WCHUNK floats = 1024 float4, 4 per thread ----
    #pragma unroll
    for (int i = tid; i < CC * WCHUNK / 4; i += NTHREADS) {
        const int c  = i >> 5;               // 32 float4 per row
        const int w4 = i & 31;
        const float4 v = *(const float4*)(in1 +
            (((size_t)b * CC + c) * HH + h) * WW + wbase + w4 * 4);
        *(float4*)&s1[c][w4 * 4] = v;
    }
    // ---- stage in2 halo tile: CC*TILE2 floats = 2048 float4, 8 per thread ----
    #pragma unroll
    for (int i = tid; i < CC * TILE2 / 4; i += NTHREADS) {
        const int c  = i >> 6;               // 64 float4 per row
        const int t4 = i & 63;
        const int wp = wbase - DD + t4 * 4;  // global w' of first elem (mult of 4)
        float4 v;
        if (wp >= 0) {
            v = *(const float4*)(in2 +
                (((size_t)b * CC + c) * HH + h) * WW + wp);
        } else {
            v = make_float4(0.f, 0.f, 0.f, 0.f);
        }
        *(float4*)&s2[c][t4 * 4] = v;
    }
    __syncthreads();

    // ---- compute: thread = (w_tile, d_tile) ----
    const int wt    = tid & 31;      // 32 w tiles of 4  -> lane id within wave
    const int dtile = tid >> 5;      // 8 d tiles of 16
    const int w0 = wt * 4;           // local w
    const int d0 = dtile * DT;
    const int t0 = w0 + d0;          // s2 index for (wi=0, di=0); t = w0+wi+d0+di

    float acc[DT][WT] = {};

    for (int c = 0; c < CC; ++c) {
        float a[WT];
        *(float4*)a = *(const float4*)&s1[c][w0];
        float bv[20];
        #pragma unroll
        for (int j = 0; j < 5; ++j)
            *(float4*)&bv[j * 4] = *(const float4*)&s2[c][t0 + j * 4];
        #pragma unroll
        for (int di = 0; di < DT; ++di)
            #pragma unroll
            for (int wi = 0; wi < WT; ++wi)
                acc[di][wi] += a[wi] * bv[di + wi];
    }

    // ---- write out ----
    const float scale = 1.0f / (float)CC;
    #pragma unroll
    for (int di = 0; di < DT; ++di) {
        const int d = d0 + di;
        float4 v = make_float4(acc[di][0] * scale, acc[di][1] * scale,
                               acc[di][2] * scale, acc[di][3] * scale);
        *(float4*)(out + (((size_t)b * DD + d) * HH + h) * WW + wbase + w0) = v;
    }
}

extern "C" void kernel_launch(void* const* d_in, const int* in_sizes, int n_in,
                              void* d_out, int out_size, void* d_ws, size_t ws_size,
                              hipStream_t stream) {
    const float* in1 = (const float*)d_in[0];
    const float* in2 = (const float*)d_in[1];
    float* out = (float*)d_out;
    const int nblocks = BB * HH * (WW / WCHUNK);   // 4096
    disp_corr_kernel<<<nblocks, NTHREADS, 0, stream>>>(in1, in2, out);
}